// Round 11
// baseline (373.037 us; speedup 1.0000x reference)
//
#include <hip/hip_runtime.h>
#include <hip/hip_bf16.h>
#include <cstdint>
#include <cstddef>

#define HD 512
#define BB 64
#define SS 2048
#define VV 32000
#define MM (SS*BB)
#define NCH 32          // s-chunks per b (64 rows each)

typedef __attribute__((ext_vector_type(8))) short bf16x8;
typedef __attribute__((ext_vector_type(4))) float f32x4;

static __device__ __forceinline__ unsigned pack2(float a, float b) {
    unsigned r;
    asm("v_cvt_pk_bf16_f32 %0, %1, %2" : "=v"(r) : "v"(a), "v"(b));
    return r;
}
static __device__ __forceinline__ float rcp_fast(float x) {
    float r; asm("v_rcp_f32 %0, %1" : "=v"(r) : "v"(x)); return r;
}
static __device__ __forceinline__ float tanh_fast(float x) {
    float e = __expf(2.f * x);
    return 1.f - 2.f * rcp_fast(e + 1.f);
}
static __device__ __forceinline__ float sigmoid_fast(float x) {
    return 1.f / (1.f + __expf(-x));
}
static __device__ __forceinline__ void gload16(const void* g, void* l) {
    __builtin_amdgcn_global_load_lds(
        (const __attribute__((address_space(1))) void*)g,
        (__attribute__((address_space(3))) void*)l, 16, 0, 0);
}

#define WAITL   asm volatile("s_waitcnt lgkmcnt(0)" ::: "memory")
#define WAITVL(N) asm volatile("s_waitcnt vmcnt(" #N ") lgkmcnt(0)" ::: "memory")
#define SBAR    __builtin_amdgcn_s_barrier()
#define SCHED   __builtin_amdgcn_sched_barrier(0)

// ---------------------------------------------------------------------------
// prep: qc[b][n] = hid[b]·Wa[n] + attn_b[n];  WeB4 = bf16(attn_W[:, H:]) LINEAR
__global__ void prep_kernel(const float* __restrict__ hid,
                            const float* __restrict__ attn_W,
                            const float* __restrict__ attn_b,
                            float* __restrict__ qc,
                            uint4* __restrict__ WeB4) {
    int i = blockIdx.x * 256 + threadIdx.x;      // 0..32767
    int n = i >> 6, b = i & 63;
    const float* hrow = hid + b * HD;
    const float* wrow = attn_W + (size_t)n * (2 * HD);
    float acc = 0.f;
    for (int k = 0; k < HD; k += 4) {
        float4 h4 = *(const float4*)(hrow + k);
        float4 w4 = *(const float4*)(wrow + k);
        acc += h4.x * w4.x + h4.y * w4.y + h4.z * w4.z + h4.w * w4.w;
    }
    qc[b * HD + n] = acc + attn_b[n];
    int col = (i << 3) & 511;
    int cc0 = col >> 3;
    const float* src = attn_W + (size_t)n * (2 * HD) + HD + col;
    float4 f0 = *(const float4*)(src);
    float4 f1 = *(const float4*)(src + 4);
    uint4 p;
    p.x = pack2(f0.x, f0.y); p.y = pack2(f0.z, f0.w);
    p.z = pack2(f1.x, f1.y); p.w = pack2(f1.z, f1.w);
    WeB4[n * 64 + cc0] = p;                       // linear storage
}

// ---------------------------------------------------------------------------
// fused attention: A through LDS (8 KB, bf16 transpose), B fragments DIRECT
// from global (L2-resident WeB4) into VGPRs — no B LDS staging, no vmem
// drain in the loop. A reg-prefetched 1 tile ahead.
__global__ __launch_bounds__(512, 4) void fattn_kernel(
    const float* __restrict__ enc,      // (S*B, 512) f32, row = s*64+b
    const uint4* __restrict__ WeB4,     // (512, 64) linear bf16 chunks
    const float* __restrict__ qc,       // (64, 512)
    const float* __restrict__ vvec,     // (512)
    float* __restrict__ oP,             // (B*NCH, 512)
    float* __restrict__ lP)             // (B*NCH)
{
    __shared__ uint4 Ald[64 * 8];       // 8 KB
    __shared__ float red[64][8];        // 2 KB
    __shared__ float p_lds[64];         // 256 B
    __shared__ float opart[8 * 512];    // 16 KB

    const int tid = threadIdx.x;
    const int wv = tid >> 6, lane = tid & 63, l15 = lane & 15, l4 = lane >> 4;
    const int b = blockIdx.x & 63;
    const int c = blockIdx.x >> 6;      // 0..31
    const int s0 = c * 64;

    f32x4 acc[4][4] = {};

    const int arow = tid >> 3;          // s-row within chunk, 0..63
    const int ac8 = tid & 7;
    const float* aptr = enc + ((size_t)(s0 + arow) * 64 + b) * HD + ac8 * 8;
    const int aslot = arow * 8 + (ac8 ^ (arow & 7));

    // per-lane B fragment base: row (wv*64 + l15), chunk l4
    const uint4* bbase = WeB4 + (size_t)(wv * 64 + l15) * 64 + l4;

    float4 pa[2][2];
    pa[0][0] = *(const float4*)(aptr);
    pa[0][1] = *(const float4*)(aptr + 4);

#pragma unroll
    for (int t = 0; t < 8; ++t) {
        const int cur = t & 1;
        if (t > 0) { WAITL; SBAR; SCHED; }   // all waves done reading Ald(t-1)
        {
            uint4 u;                          // pack A(t); auto-waits pa[cur]
            u.x = pack2(pa[cur][0].x, pa[cur][0].y);
            u.y = pack2(pa[cur][0].z, pa[cur][0].w);
            u.z = pack2(pa[cur][1].x, pa[cur][1].y);
            u.w = pack2(pa[cur][1].z, pa[cur][1].w);
            Ald[aslot] = u;
        }
        if (t < 7) {                          // issue A(t+1); flies across barrier
            pa[cur ^ 1][0] = *(const float4*)(aptr + (t + 1) * 64);
            pa[cur ^ 1][1] = *(const float4*)(aptr + (t + 1) * 64 + 4);
        }
        WAITL; SBAR; SCHED;                   // Ald(t) visible; vmem NOT drained

#pragma unroll
        for (int ks = 0; ks < 2; ++ks) {
            const int chunk = ks * 4 + l4;
            bf16x8 af[4], bfr[4];
#pragma unroll
            for (int mi = 0; mi < 4; ++mi) {
                int row = mi * 16 + l15;
                af[mi] = *(const bf16x8*)&Ald[row * 8 + (chunk ^ (row & 7))];
            }
#pragma unroll
            for (int ni = 0; ni < 4; ++ni)
                bfr[ni] = *(const bf16x8*)(bbase + ni * 16 * 64 + t * 8 + ks * 4);
#pragma unroll
            for (int mi = 0; mi < 4; ++mi)
#pragma unroll
                for (int ni = 0; ni < 4; ++ni)
                    acc[mi][ni] = __builtin_amdgcn_mfma_f32_16x16x32_bf16(
                        af[mi], bfr[ni], acc[mi][ni], 0, 0, 0);
        }
    }

    // ---- scores: tanh + dot v, reduce across 512 n
    float vv[4], qn[4];
#pragma unroll
    for (int ni = 0; ni < 4; ++ni) {
        int n = wv * 64 + ni * 16 + l15;
        vv[ni] = vvec[n];
        qn[ni] = qc[b * HD + n];
    }
#pragma unroll
    for (int mi = 0; mi < 4; ++mi) {
#pragma unroll
        for (int r = 0; r < 4; ++r) {
            const int rowl = mi * 16 + l4 * 4 + r;   // s-row 0..63
            float s = 0.f;
#pragma unroll
            for (int ni = 0; ni < 4; ++ni)
                s += tanh_fast(acc[mi][ni][r] + qn[ni]) * vv[ni];
#pragma unroll
            for (int msk = 8; msk >= 1; msk >>= 1)
                s += __shfl_xor(s, msk);
            if (l15 == 0) red[rowl][wv] = s;
        }
    }
    __syncthreads();
    if (tid < 64) {                      // wave 0
        float t = ((red[tid][0] + red[tid][1]) + (red[tid][2] + red[tid][3]))
                + ((red[tid][4] + red[tid][5]) + (red[tid][6] + red[tid][7]));
        float p = __expf(t);             // |t| <= sum|v| ~ 20: safe
        p_lds[tid] = p;
        float l = p;
#pragma unroll
        for (int msk = 32; msk >= 1; msk >>= 1) l += __shfl_xor(l, msk);
        if (tid == 0) lP[b * NCH + c] = l;
    }
    __syncthreads();

    // ---- o-phase: wave wv owns s-rows wv*8..+7, lane owns h = lane*8..+7
    float o8[8] = {};
    const float* ebase = enc + ((size_t)(s0 + wv * 8) * 64 + b) * HD + lane * 8;
#pragma unroll
    for (int i = 0; i < 8; ++i) {
        float w = p_lds[wv * 8 + i];
        const float* ep = ebase + (size_t)i * 64 * HD;
        float4 e0 = *(const float4*)(ep);
        float4 e1 = *(const float4*)(ep + 4);
        o8[0] += w * e0.x; o8[1] += w * e0.y; o8[2] += w * e0.z; o8[3] += w * e0.w;
        o8[4] += w * e1.x; o8[5] += w * e1.y; o8[6] += w * e1.z; o8[7] += w * e1.w;
    }
    {
        float4* dst = (float4*)&opart[wv * 512 + lane * 8];
        float4 w0 = {o8[0], o8[1], o8[2], o8[3]};
        float4 w1 = {o8[4], o8[5], o8[6], o8[7]};
        dst[0] = w0; dst[1] = w1;
    }
    __syncthreads();
    float o = 0.f;
#pragma unroll
    for (int w = 0; w < 8; ++w) o += opart[w * 512 + tid];
    oP[((size_t)b * NCH + c) * HD + tid] = o;
}

// ---------------------------------------------------------------------------
// combine partials -> context; write x (emb gather + ctx) and y_bf ctx half
__global__ void combine_kernel(const float* __restrict__ oP,
                               const float* __restrict__ lP,
                               const int* __restrict__ word,
                               const float* __restrict__ emb,
                               float* __restrict__ x,
                               unsigned* __restrict__ y_bf) {
    const int b = blockIdx.x;
    const int tid = threadIdx.x;    // 512
    __shared__ float ctx_lds[512];
    float L = 0.f;
#pragma unroll 8
    for (int c = 0; c < NCH; ++c) L += lP[b * NCH + c];
    float o = 0.f;
#pragma unroll 4
    for (int c = 0; c < NCH; ++c)
        o += oP[((size_t)b * NCH + c) * HD + tid];
    float ctx = o / L;
    x[b * 1024 + HD + tid] = ctx;
    ctx_lds[tid] = ctx;
    x[b * 1024 + tid] = emb[(size_t)word[b] * HD + tid];
    __syncthreads();
    if (tid < 256)
        y_bf[b * 512 + 256 + tid] = pack2(ctx_lds[2 * tid], ctx_lds[2 * tid + 1]);
}

// ---------------------------------------------------------------------------
__global__ void gates_kernel(const float* __restrict__ x,
                             const float* __restrict__ hid,
                             const float* __restrict__ W_ih,
                             const float* __restrict__ W_hh,
                             const float* __restrict__ b_ih,
                             const float* __restrict__ b_hh,
                             float* __restrict__ gi, float* __restrict__ gh) {
    const int tid = threadIdx.x;
    const int b = tid & 63;
    const int j = blockIdx.x * 4 + (tid >> 6);
    float agi = 0.f, agh = 0.f;
    const float* xr = x + b * 1024;
    const float* wr = W_ih + (size_t)j * 1024;
    for (int k = 0; k < 1024; k += 4) {
        float4 xv = *(const float4*)(xr + k);
        float4 w4 = *(const float4*)(wr + k);
        agi += xv.x * w4.x + xv.y * w4.y + xv.z * w4.z + xv.w * w4.w;
    }
    const float* hr = hid + b * HD;
    const float* wh = W_hh + (size_t)j * HD;
    for (int k = 0; k < HD; k += 4) {
        float4 hv = *(const float4*)(hr + k);
        float4 w4 = *(const float4*)(wh + k);
        agh += hv.x * w4.x + hv.y * w4.y + hv.z * w4.z + hv.w * w4.w;
    }
    gi[b * 1536 + j] = agi + b_ih[j];
    gh[b * 1536 + j] = agh + b_hh[j];
}

__global__ void hnew_kernel(const float* __restrict__ gi,
                            const float* __restrict__ gh,
                            const float* __restrict__ hid,
                            float* __restrict__ out_h,
                            unsigned* __restrict__ y_bf) {
    const int b = blockIdx.x;
    const int h = threadIdx.x * 2;           // 256 thr
    float hn[2];
#pragma unroll
    for (int j = 0; j < 2; ++j) {
        int hh = h + j;
        float r = sigmoid_fast(gi[b * 1536 + hh] + gh[b * 1536 + hh]);
        float z = sigmoid_fast(gi[b * 1536 + 512 + hh] + gh[b * 1536 + 512 + hh]);
        float n = tanh_fast(gi[b * 1536 + 1024 + hh] + r * gh[b * 1536 + 1024 + hh]);
        hn[j] = (1.f - z) * n + z * hid[b * HD + hh];
        out_h[b * HD + hh] = hn[j];
    }
    y_bf[b * 512 + (h >> 1)] = pack2(hn[0], hn[1]);
}

// ---------------------------------------------------------------------------
// logits: BM=64, BN=64, BK=64, K=1024 (16 iters), 256 thr (4 waves), grid 500.
__global__ __launch_bounds__(256, 4) void logits_kernel(
    const unsigned short* __restrict__ y_bf,  // (64, 1024) bf16
    const float* __restrict__ out_W,          // (V, 1024)
    const float* __restrict__ out_b,
    float* __restrict__ logits)               // (64, V)
{
    __shared__ uint4 Yld[64 * 8];      // 8 KB
    __shared__ uint4 Wld[64 * 8];      // 8 KB
    const int tid = threadIdx.x;
    const int wv = tid >> 6, lane = tid & 63, l15 = lane & 15, l4 = lane >> 4;
    const int n0 = blockIdx.x * 64;

    f32x4 acc[4] = {};

    const int s1 = tid, s2 = tid + 256;
    const int r1 = s1 >> 3, g1 = (s1 & 7) ^ (r1 & 7);
    const int r2 = s2 >> 3, g2 = (s2 & 7) ^ (r2 & 7);
    const unsigned short* ya1 = y_bf + (size_t)r1 * 1024 + g1 * 8;
    const unsigned short* ya2 = y_bf + (size_t)r2 * 1024 + g2 * 8;

    const int wr = tid >> 3, wc8 = tid & 7;   // rows wr, wr+32
    const int wsl = wc8 ^ (wr & 7);
    const float* wp0 = out_W + (size_t)(n0 + wr) * 1024 + wc8 * 8;
    const float* wp1 = out_W + (size_t)(n0 + wr + 32) * 1024 + wc8 * 8;

    float4 pw[2][4];
    pw[0][0] = *(const float4*)(wp0);
    pw[0][1] = *(const float4*)(wp0 + 4);
    pw[0][2] = *(const float4*)(wp1);
    pw[0][3] = *(const float4*)(wp1 + 4);

#pragma unroll
    for (int t = 0; t < 16; ++t) {
        const int cur = t & 1;
        if (t > 0) {
            WAITL; SBAR; SCHED;
        }
        gload16(ya1 + t * 64, &Yld[s1]);          // A first (oldest)
        gload16(ya2 + t * 64, &Yld[s2]);
        {
            uint4 u;
            u.x = pack2(pw[cur][0].x, pw[cur][0].y);
            u.y = pack2(pw[cur][0].z, pw[cur][0].w);
            u.z = pack2(pw[cur][1].x, pw[cur][1].y);
            u.w = pack2(pw[cur][1].z, pw[cur][1].w);
            Wld[wr * 8 + wsl] = u;
            u.x = pack2(pw[cur][2].x, pw[cur][2].y);
            u.y = pack2(pw[cur][2].z, pw[cur][2].w);
            u.z = pack2(pw[cur][3].x, pw[cur][3].y);
            u.w = pack2(pw[cur][3].z, pw[cur][3].w);
            Wld[(wr + 32) * 8 + wsl] = u;
        }
        if (t < 15) {
            const int k1 = (t + 1) * 64;
            pw[cur ^ 1][0] = *(const float4*)(wp0 + k1);
            pw[cur ^ 1][1] = *(const float4*)(wp0 + k1 + 4);
            pw[cur ^ 1][2] = *(const float4*)(wp1 + k1);
            pw[cur ^ 1][3] = *(const float4*)(wp1 + k1 + 4);
            WAITVL(4);                   // A gloads done; W(t+1) flies
        } else {
            WAITVL(0);
        }
        SBAR; SCHED;

#pragma unroll
        for (int ks = 0; ks < 2; ++ks) {
            const int chunk = ks * 4 + l4;
            bf16x8 af[4], bfr;
#pragma unroll
            for (int mi = 0; mi < 4; ++mi) {
                int row = mi * 16 + l15;
                af[mi] = *(const bf16x8*)&Yld[row * 8 + (chunk ^ (row & 7))];
            }
            {
                int row = wv * 16 + l15;
                bfr = *(const bf16x8*)&Wld[row * 8 + (chunk ^ (row & 7))];
            }
#pragma unroll
            for (int mi = 0; mi < 4; ++mi)
                acc[mi] = __builtin_amdgcn_mfma_f32_16x16x32_bf16(
                    af[mi], bfr, acc[mi], 0, 0, 0);
        }
    }
#pragma unroll
    for (int mi = 0; mi < 4; ++mi) {
#pragma unroll
        for (int r = 0; r < 4; ++r) {
            const int b = mi * 16 + l4 * 4 + r;
            int n = n0 + wv * 16 + l15;
            logits[(size_t)b * VV + n] = acc[mi][r] + out_b[n];
        }
    }
}

// ---------------------------------------------------------------------------
// log_softmax, 2-phase: grid 320 (= 64 rows x 5 chunks of 6400), 256 thr
__global__ void lsm1_kernel(const float* __restrict__ logits,
                            float* __restrict__ part) {
    const int bid = blockIdx.x;
    const int b = bid / 5, q = bid - b * 5;
    const int tid = threadIdx.x;  // 256
    __shared__ float sm[256];
    const float* row = logits + (size_t)b * VV + q * 6400;
    float m = -1e30f;
    for (int i = tid; i < 6400; i += 256) m = fmaxf(m, row[i]);
    sm[tid] = m; __syncthreads();
    for (int o = 128; o > 0; o >>= 1) {
        if (tid < o) sm[tid] = fmaxf(sm[tid], sm[tid + o]);
        __syncthreads();
    }
    m = sm[0]; __syncthreads();
    float s = 0.f;
    for (int i = tid; i < 6400; i += 256) s += __expf(row[i] - m);
    sm[tid] = s; __syncthreads();
    for (int o = 128; o > 0; o >>= 1) {
        if (tid < o) sm[tid] += sm[tid + o];
        __syncthreads();
    }
    if (tid == 0) { part[bid * 2] = m; part[bid * 2 + 1] = sm[0]; }
}

__global__ void lsm2_kernel(float* __restrict__ logits,
                            const float* __restrict__ part) {
    const int bid = blockIdx.x;
    const int b = bid / 5, q = bid - b * 5;
    const int tid = threadIdx.x;  // 256
    float m = -1e30f;
#pragma unroll
    for (int c = 0; c < 5; ++c) m = fmaxf(m, part[(b * 5 + c) * 2]);
    float L = 0.f;
#pragma unroll
    for (int c = 0; c < 5; ++c)
        L += part[(b * 5 + c) * 2 + 1] * __expf(part[(b * 5 + c) * 2] - m);
    float lse = m + __logf(L);
    float* row = logits + (size_t)b * VV + q * 6400;
    for (int i = tid; i < 6400; i += 256) row[i] -= lse;
}

// ---------------------------------------------------------------------------
extern "C" void kernel_launch(void* const* d_in, const int* in_sizes, int n_in,
                              void* d_out, int out_size, void* d_ws, size_t ws_size,
                              hipStream_t stream) {
    (void)in_sizes; (void)n_in; (void)out_size; (void)ws_size;
    const int*   word   = (const int*)d_in[0];
    const float* hid    = (const float*)d_in[1];
    const float* enc    = (const float*)d_in[2];
    const float* emb    = (const float*)d_in[3];
    const float* attn_W = (const float*)d_in[4];
    const float* attn_b = (const float*)d_in[5];
    const float* v      = (const float*)d_in[6];
    const float* W_ih   = (const float*)d_in[7];
    const float* W_hh   = (const float*)d_in[8];
    const float* b_ih   = (const float*)d_in[9];
    const float* b_hh   = (const float*)d_in[10];
    const float* out_W  = (const float*)d_in[11];
    const float* out_b  = (const float*)d_in[12];

    float* out    = (float*)d_out;
    float* logits = out;                         // (B, V)
    float* out_h  = out + (size_t)BB * VV;       // (B, H)

    char* ws0 = (char*)d_ws;
    size_t off = 0;
    float* qc      = (float*)(ws0 + off);    off += 64 * 512 * 4;
    uint4* WeB4    = (uint4*)(ws0 + off);    off += 512 * 512 * 2;
    float* oP      = (float*)(ws0 + off);    off += (size_t)BB * NCH * HD * 4;
    float* lP      = (float*)(ws0 + off);    off += BB * NCH * 4;
    float* x       = (float*)(ws0 + off);    off += 64 * 1024 * 4;
    unsigned* y_bf = (unsigned*)(ws0 + off); off += 64 * 1024 * 2;
    float* gi      = (float*)(ws0 + off);    off += 64 * 1536 * 4;
    float* gh      = (float*)(ws0 + off);    off += 64 * 1536 * 4;
    float* lsmp    = (float*)(ws0 + off);    off += 320 * 2 * 4;

    prep_kernel<<<128, 256, 0, stream>>>(hid, attn_W, attn_b, qc, WeB4);
    fattn_kernel<<<BB * NCH, 512, 0, stream>>>(enc, WeB4, qc, v, oP, lP);
    combine_kernel<<<BB, 512, 0, stream>>>(oP, lP, word, emb, x, y_bf);
    gates_kernel<<<384, 256, 0, stream>>>(x, hid, W_ih, W_hh, b_ih, b_hh, gi, gh);
    hnew_kernel<<<BB, 256, 0, stream>>>(gi, gh, hid, out_h, y_bf);
    logits_kernel<<<VV / 64, 256, 0, stream>>>((const unsigned short*)y_bf, out_W, out_b, logits);
    lsm1_kernel<<<320, 256, 0, stream>>>(logits, lsmp);
    lsm2_kernel<<<320, 256, 0, stream>>>(logits, lsmp);
}

// Round 12
// 321.607 us; speedup vs baseline: 1.1599x; 1.1599x over previous
//
#include <hip/hip_runtime.h>
#include <hip/hip_bf16.h>
#include <cstdint>
#include <cstddef>

#define HD 512
#define BB 64
#define SS 2048
#define VV 32000
#define MM (SS*BB)
#define NCH 32          // s-chunks per b (64 rows each)

typedef __attribute__((ext_vector_type(8))) short bf16x8;
typedef __attribute__((ext_vector_type(4))) float f32x4;

static __device__ __forceinline__ unsigned pack2(float a, float b) {
    unsigned r;
    asm("v_cvt_pk_bf16_f32 %0, %1, %2" : "=v"(r) : "v"(a), "v"(b));
    return r;
}
static __device__ __forceinline__ float rcp_fast(float x) {
    float r; asm("v_rcp_f32 %0, %1" : "=v"(r) : "v"(x)); return r;
}
static __device__ __forceinline__ float tanh_fast(float x) {
    float e = __expf(2.f * x);
    return 1.f - 2.f * rcp_fast(e + 1.f);
}
static __device__ __forceinline__ float sigmoid_fast(float x) {
    return 1.f / (1.f + __expf(-x));
}
static __device__ __forceinline__ void gload16(const void* g, void* l) {
    __builtin_amdgcn_global_load_lds(
        (const __attribute__((address_space(1))) void*)g,
        (__attribute__((address_space(3))) void*)l, 16, 0, 0);
}

#define WAITL   asm volatile("s_waitcnt lgkmcnt(0)" ::: "memory")
#define WAITVL(N) asm volatile("s_waitcnt vmcnt(" #N ") lgkmcnt(0)" ::: "memory")
#define SBAR    __builtin_amdgcn_s_barrier()
#define SCHED   __builtin_amdgcn_sched_barrier(0)

// ---------------------------------------------------------------------------
// prep: qc[b][n] = hid[b]·Wa[n] + attn_b[n]
//       WeF = bf16(attn_W[:, H:]) in FRAGMENT-CONTIGUOUS layout:
//       WeF[(((wv*8+t)*2+ks)*4+ni)*64 + lane] holds row wv*64+ni*16+(lane&15),
//       bf16 k-octet chunk t*8+ks*4+(lane>>4).
__global__ void prep_kernel(const float* __restrict__ hid,
                            const float* __restrict__ attn_W,
                            const float* __restrict__ attn_b,
                            float* __restrict__ qc,
                            uint4* __restrict__ WeF) {
    int i = blockIdx.x * 256 + threadIdx.x;      // 0..32767
    int n = i >> 6;
    int cc = i & 63;
    int b = i & 63;
    const float* hrow = hid + b * HD;
    const float* wrow = attn_W + (size_t)n * (2 * HD);
    float acc = 0.f;
    for (int k = 0; k < HD; k += 4) {
        float4 h4 = *(const float4*)(hrow + k);
        float4 w4 = *(const float4*)(wrow + k);
        acc += h4.x * w4.x + h4.y * w4.y + h4.z * w4.z + h4.w * w4.w;
    }
    qc[b * HD + n] = acc + attn_b[n];
    // convert chunk cc of row n
    const float* src = attn_W + (size_t)n * (2 * HD) + HD + cc * 8;
    float4 f0 = *(const float4*)(src);
    float4 f1 = *(const float4*)(src + 4);
    uint4 p;
    p.x = pack2(f0.x, f0.y); p.y = pack2(f0.z, f0.w);
    p.z = pack2(f1.x, f1.y); p.w = pack2(f1.z, f1.w);
    int wv = n >> 6, ni = (n >> 4) & 3, l15 = n & 15;
    int t = cc >> 3, ks = (cc >> 2) & 1, l4 = cc & 3;
    int lane = l4 * 16 + l15;
    WeF[((((wv * 8 + t) * 2 + ks) * 4 + ni) << 6) + lane] = p;
}

// ---------------------------------------------------------------------------
// fused attention: A staged ONCE full-K in LDS (64 KB); K-loop has ZERO
// barriers — B fragments loaded coalesced from L2 (fragment-major WeF),
// af from read-only LDS, waves free-run.
__global__ __launch_bounds__(512, 4) void fattn_kernel(
    const float* __restrict__ enc,      // (S*B, 512) f32, row = s*64+b
    const uint4* __restrict__ WeF,      // (32768) fragment-major bf16 chunks
    const float* __restrict__ qc,       // (64, 512)
    const float* __restrict__ vvec,     // (512)
    float* __restrict__ oP,             // (B*NCH, 512)
    float* __restrict__ lP)             // (B*NCH)
{
    __shared__ char smem[65536 + 2048 + 256];
    uint4* Ald = (uint4*)smem;                          // 64 KB: 64 rows x 64 chunks
    float (*red)[8] = (float(*)[8])(smem + 65536);      // 2 KB
    float* p_lds = (float*)(smem + 65536 + 2048);       // 256 B
    float* opart = (float*)smem;                        // aliases Ald (16 KB)

    const int tid = threadIdx.x;
    const int wv = tid >> 6, lane = tid & 63, l15 = lane & 15, l4 = lane >> 4;
    const int b = blockIdx.x & 63;
    const int c = blockIdx.x >> 6;      // 0..31
    const int s0 = c * 64;

    // ---- stage full A tile (64 rows x 512 k, bf16, swizzled low-3 chunk)
    {
        const int arow = tid >> 3, a8 = tid & 7;
        const float* ap = enc + ((size_t)(s0 + arow) * 64 + b) * HD;
#pragma unroll
        for (int j = 0; j < 8; ++j) {
            int cc = j * 8 + a8;
            float4 f0 = *(const float4*)(ap + cc * 8);
            float4 f1 = *(const float4*)(ap + cc * 8 + 4);
            uint4 u;
            u.x = pack2(f0.x, f0.y); u.y = pack2(f0.z, f0.w);
            u.z = pack2(f1.x, f1.y); u.w = pack2(f1.z, f1.w);
            Ald[arow * 64 + j * 8 + (a8 ^ (arow & 7))] = u;
        }
    }
    __syncthreads();

    f32x4 acc[4][4] = {};
    const uint4* bbase = WeF + wv * 4096 + lane;   // + (t*512 + ks*256 + ni*64)

    // ---- K loop: no barriers, no waitcnt — compiler schedules freely
#pragma unroll
    for (int t = 0; t < 8; ++t) {
#pragma unroll
        for (int ks = 0; ks < 2; ++ks) {
            bf16x8 af[4], bfr[4];
#pragma unroll
            for (int mi = 0; mi < 4; ++mi) {
                int row = mi * 16 + l15;
                af[mi] = *(const bf16x8*)&Ald[row * 64 + t * 8
                                              + ((ks * 4 + l4) ^ (row & 7))];
            }
#pragma unroll
            for (int ni = 0; ni < 4; ++ni)
                bfr[ni] = *(const bf16x8*)(bbase + t * 512 + ks * 256 + ni * 64);
#pragma unroll
            for (int mi = 0; mi < 4; ++mi)
#pragma unroll
                for (int ni = 0; ni < 4; ++ni)
                    acc[mi][ni] = __builtin_amdgcn_mfma_f32_16x16x32_bf16(
                        af[mi], bfr[ni], acc[mi][ni], 0, 0, 0);
        }
    }

    // ---- scores: tanh + dot v, reduce across 512 n
    float vv[4], qn[4];
#pragma unroll
    for (int ni = 0; ni < 4; ++ni) {
        int n = wv * 64 + ni * 16 + l15;
        vv[ni] = vvec[n];
        qn[ni] = qc[b * HD + n];
    }
#pragma unroll
    for (int mi = 0; mi < 4; ++mi) {
#pragma unroll
        for (int r = 0; r < 4; ++r) {
            const int rowl = mi * 16 + l4 * 4 + r;   // s-row 0..63
            float s = 0.f;
#pragma unroll
            for (int ni = 0; ni < 4; ++ni)
                s += tanh_fast(acc[mi][ni][r] + qn[ni]) * vv[ni];
#pragma unroll
            for (int msk = 8; msk >= 1; msk >>= 1)
                s += __shfl_xor(s, msk);
            if (l15 == 0) red[rowl][wv] = s;
        }
    }
    __syncthreads();        // all waves past K-loop: Ald dead, opart safe
    if (tid < 64) {         // wave 0
        float t = ((red[tid][0] + red[tid][1]) + (red[tid][2] + red[tid][3]))
                + ((red[tid][4] + red[tid][5]) + (red[tid][6] + red[tid][7]));
        float p = __expf(t);             // |t| <= sum|v| ~ 20: safe
        p_lds[tid] = p;
        float l = p;
#pragma unroll
        for (int msk = 32; msk >= 1; msk >>= 1) l += __shfl_xor(l, msk);
        if (tid == 0) lP[b * NCH + c] = l;
    }
    __syncthreads();

    // ---- o-phase: wave wv owns s-rows wv*8..+7, lane owns h = lane*8..+7
    float o8[8] = {};
    const float* ebase = enc + ((size_t)(s0 + wv * 8) * 64 + b) * HD + lane * 8;
#pragma unroll
    for (int i = 0; i < 8; ++i) {
        float w = p_lds[wv * 8 + i];
        const float* ep = ebase + (size_t)i * 64 * HD;
        float4 e0 = *(const float4*)(ep);
        float4 e1 = *(const float4*)(ep + 4);
        o8[0] += w * e0.x; o8[1] += w * e0.y; o8[2] += w * e0.z; o8[3] += w * e0.w;
        o8[4] += w * e1.x; o8[5] += w * e1.y; o8[6] += w * e1.z; o8[7] += w * e1.w;
    }
    {
        float4* dst = (float4*)&opart[wv * 512 + lane * 8];
        float4 w0 = {o8[0], o8[1], o8[2], o8[3]};
        float4 w1 = {o8[4], o8[5], o8[6], o8[7]};
        dst[0] = w0; dst[1] = w1;
    }
    __syncthreads();
    float o = 0.f;
#pragma unroll
    for (int w = 0; w < 8; ++w) o += opart[w * 512 + tid];
    oP[((size_t)b * NCH + c) * HD + tid] = o;
}

// ---------------------------------------------------------------------------
// combine partials -> context; write x (emb gather + ctx) and y_bf ctx half
__global__ void combine_kernel(const float* __restrict__ oP,
                               const float* __restrict__ lP,
                               const int* __restrict__ word,
                               const float* __restrict__ emb,
                               float* __restrict__ x,
                               unsigned* __restrict__ y_bf) {
    const int b = blockIdx.x;
    const int tid = threadIdx.x;    // 512
    __shared__ float ctx_lds[512];
    float L = 0.f;
#pragma unroll 8
    for (int c = 0; c < NCH; ++c) L += lP[b * NCH + c];
    float o = 0.f;
#pragma unroll 4
    for (int c = 0; c < NCH; ++c)
        o += oP[((size_t)b * NCH + c) * HD + tid];
    float ctx = o / L;
    x[b * 1024 + HD + tid] = ctx;
    ctx_lds[tid] = ctx;
    x[b * 1024 + tid] = emb[(size_t)word[b] * HD + tid];
    __syncthreads();
    if (tid < 256)
        y_bf[b * 512 + 256 + tid] = pack2(ctx_lds[2 * tid], ctx_lds[2 * tid + 1]);
}

// ---------------------------------------------------------------------------
__global__ void gates_kernel(const float* __restrict__ x,
                             const float* __restrict__ hid,
                             const float* __restrict__ W_ih,
                             const float* __restrict__ W_hh,
                             const float* __restrict__ b_ih,
                             const float* __restrict__ b_hh,
                             float* __restrict__ gi, float* __restrict__ gh) {
    const int tid = threadIdx.x;
    const int b = tid & 63;
    const int j = blockIdx.x * 4 + (tid >> 6);
    float agi = 0.f, agh = 0.f;
    const float* xr = x + b * 1024;
    const float* wr = W_ih + (size_t)j * 1024;
    for (int k = 0; k < 1024; k += 4) {
        float4 xv = *(const float4*)(xr + k);
        float4 w4 = *(const float4*)(wr + k);
        agi += xv.x * w4.x + xv.y * w4.y + xv.z * w4.z + xv.w * w4.w;
    }
    const float* hr = hid + b * HD;
    const float* wh = W_hh + (size_t)j * HD;
    for (int k = 0; k < HD; k += 4) {
        float4 hv = *(const float4*)(hr + k);
        float4 w4 = *(const float4*)(wh + k);
        agh += hv.x * w4.x + hv.y * w4.y + hv.z * w4.z + hv.w * w4.w;
    }
    gi[b * 1536 + j] = agi + b_ih[j];
    gh[b * 1536 + j] = agh + b_hh[j];
}

__global__ void hnew_kernel(const float* __restrict__ gi,
                            const float* __restrict__ gh,
                            const float* __restrict__ hid,
                            float* __restrict__ out_h,
                            unsigned* __restrict__ y_bf) {
    const int b = blockIdx.x;
    const int h = threadIdx.x * 2;           // 256 thr
    float hn[2];
#pragma unroll
    for (int j = 0; j < 2; ++j) {
        int hh = h + j;
        float r = sigmoid_fast(gi[b * 1536 + hh] + gh[b * 1536 + hh]);
        float z = sigmoid_fast(gi[b * 1536 + 512 + hh] + gh[b * 1536 + 512 + hh]);
        float n = tanh_fast(gi[b * 1536 + 1024 + hh] + r * gh[b * 1536 + 1024 + hh]);
        hn[j] = (1.f - z) * n + z * hid[b * HD + hh];
        out_h[b * HD + hh] = hn[j];
    }
    y_bf[b * 512 + (h >> 1)] = pack2(hn[0], hn[1]);
}

// ---------------------------------------------------------------------------
// logits: BM=64, BN=64, BK=64, K=1024 (16 iters), 256 thr (4 waves), grid 500.
__global__ __launch_bounds__(256, 4) void logits_kernel(
    const unsigned short* __restrict__ y_bf,  // (64, 1024) bf16
    const float* __restrict__ out_W,          // (V, 1024)
    const float* __restrict__ out_b,
    float* __restrict__ logits)               // (64, V)
{
    __shared__ uint4 Yld[64 * 8];      // 8 KB
    __shared__ uint4 Wld[64 * 8];      // 8 KB
    const int tid = threadIdx.x;
    const int wv = tid >> 6, lane = tid & 63, l15 = lane & 15, l4 = lane >> 4;
    const int n0 = blockIdx.x * 64;

    f32x4 acc[4] = {};

    const int s1 = tid, s2 = tid + 256;
    const int r1 = s1 >> 3, g1 = (s1 & 7) ^ (r1 & 7);
    const int r2 = s2 >> 3, g2 = (s2 & 7) ^ (r2 & 7);
    const unsigned short* ya1 = y_bf + (size_t)r1 * 1024 + g1 * 8;
    const unsigned short* ya2 = y_bf + (size_t)r2 * 1024 + g2 * 8;

    const int wr = tid >> 3, wc8 = tid & 7;   // rows wr, wr+32
    const int wsl = wc8 ^ (wr & 7);
    const float* wp0 = out_W + (size_t)(n0 + wr) * 1024 + wc8 * 8;
    const float* wp1 = out_W + (size_t)(n0 + wr + 32) * 1024 + wc8 * 8;

    float4 pw[2][4];
    pw[0][0] = *(const float4*)(wp0);
    pw[0][1] = *(const float4*)(wp0 + 4);
    pw[0][2] = *(const float4*)(wp1);
    pw[0][3] = *(const float4*)(wp1 + 4);

#pragma unroll
    for (int t = 0; t < 16; ++t) {
        const int cur = t & 1;
        if (t > 0) {
            WAITL; SBAR; SCHED;
        }
        gload16(ya1 + t * 64, &Yld[s1]);          // A first (oldest)
        gload16(ya2 + t * 64, &Yld[s2]);
        {
            uint4 u;
            u.x = pack2(pw[cur][0].x, pw[cur][0].y);
            u.y = pack2(pw[cur][0].z, pw[cur][0].w);
            u.z = pack2(pw[cur][1].x, pw[cur][1].y);
            u.w = pack2(pw[cur][1].z, pw[cur][1].w);
            Wld[wr * 8 + wsl] = u;
            u.x = pack2(pw[cur][2].x, pw[cur][2].y);
            u.y = pack2(pw[cur][2].z, pw[cur][2].w);
            u.z = pack2(pw[cur][3].x, pw[cur][3].y);
            u.w = pack2(pw[cur][3].z, pw[cur][3].w);
            Wld[(wr + 32) * 8 + wsl] = u;
        }
        if (t < 15) {
            const int k1 = (t + 1) * 64;
            pw[cur ^ 1][0] = *(const float4*)(wp0 + k1);
            pw[cur ^ 1][1] = *(const float4*)(wp0 + k1 + 4);
            pw[cur ^ 1][2] = *(const float4*)(wp1 + k1);
            pw[cur ^ 1][3] = *(const float4*)(wp1 + k1 + 4);
            WAITVL(4);                   // A gloads done; W(t+1) flies
        } else {
            WAITVL(0);
        }
        SBAR; SCHED;

#pragma unroll
        for (int ks = 0; ks < 2; ++ks) {
            const int chunk = ks * 4 + l4;
            bf16x8 af[4], bfr;
#pragma unroll
            for (int mi = 0; mi < 4; ++mi) {
                int row = mi * 16 + l15;
                af[mi] = *(const bf16x8*)&Yld[row * 8 + (chunk ^ (row & 7))];
            }
            {
                int row = wv * 16 + l15;
                bfr = *(const bf16x8*)&Wld[row * 8 + (chunk ^ (row & 7))];
            }
#pragma unroll
            for (int mi = 0; mi < 4; ++mi)
                acc[mi] = __builtin_amdgcn_mfma_f32_16x16x32_bf16(
                    af[mi], bfr, acc[mi], 0, 0, 0);
        }
    }
#pragma unroll
    for (int mi = 0; mi < 4; ++mi) {
#pragma unroll
        for (int r = 0; r < 4; ++r) {
            const int b = mi * 16 + l4 * 4 + r;
            int n = n0 + wv * 16 + l15;
            logits[(size_t)b * VV + n] = acc[mi][r] + out_b[n];
        }
    }
}

// ---------------------------------------------------------------------------
// log_softmax, 2-phase: grid 320 (= 64 rows x 5 chunks of 6400), 256 thr
__global__ void lsm1_kernel(const float* __restrict__ logits,
                            float* __restrict__ part) {
    const int bid = blockIdx.x;
    const int b = bid / 5, q = bid - b * 5;
    const int tid = threadIdx.x;  // 256
    __shared__ float sm[256];
    const float* row = logits + (size_t)b * VV + q * 6400;
    float m = -1e30f;
    for (int i = tid; i < 6400; i += 256) m = fmaxf(m, row[i]);
    sm[tid] = m; __syncthreads();
    for (int o = 128; o > 0; o >>= 1) {
        if (tid < o) sm[tid] = fmaxf(sm[tid], sm[tid + o]);
        __syncthreads();
    }
    m = sm[0]; __syncthreads();
    float s = 0.f;
    for (int i = tid; i < 6400; i += 256) s += __expf(row[i] - m);
    sm[tid] = s; __syncthreads();
    for (int o = 128; o > 0; o >>= 1) {
        if (tid < o) sm[tid] += sm[tid + o];
        __syncthreads();
    }
    if (tid == 0) { part[bid * 2] = m; part[bid * 2 + 1] = sm[0]; }
}

__global__ void lsm2_kernel(float* __restrict__ logits,
                            const float* __restrict__ part) {
    const int bid = blockIdx.x;
    const int b = bid / 5, q = bid - b * 5;
    const int tid = threadIdx.x;  // 256
    float m = -1e30f;
#pragma unroll
    for (int c = 0; c < 5; ++c) m = fmaxf(m, part[(b * 5 + c) * 2]);
    float L = 0.f;
#pragma unroll
    for (int c = 0; c < 5; ++c)
        L += part[(b * 5 + c) * 2 + 1] * __expf(part[(b * 5 + c) * 2] - m);
    float lse = m + __logf(L);
    float* row = logits + (size_t)b * VV + q * 6400;
    for (int i = tid; i < 6400; i += 256) row[i] -= lse;
}

// ---------------------------------------------------------------------------
extern "C" void kernel_launch(void* const* d_in, const int* in_sizes, int n_in,
                              void* d_out, int out_size, void* d_ws, size_t ws_size,
                              hipStream_t stream) {
    (void)in_sizes; (void)n_in; (void)out_size; (void)ws_size;
    const int*   word   = (const int*)d_in[0];
    const float* hid    = (const float*)d_in[1];
    const float* enc    = (const float*)d_in[2];
    const float* emb    = (const float*)d_in[3];
    const float* attn_W = (const float*)d_in[4];
    const float* attn_b = (const float*)d_in[5];
    const float* v      = (const float*)d_in[6];
    const float* W_ih   = (const float*)d_in[7];
    const float* W_hh   = (const float*)d_in[8];
    const float* b_ih   = (const float*)d_in[9];
    const float* b_hh   = (const float*)d_in[10];
    const float* out_W  = (const float*)d_in[11];
    const float* out_b  = (const float*)d_in[12];

    float* out    = (float*)d_out;
    float* logits = out;                         // (B, V)
    float* out_h  = out + (size_t)BB * VV;       // (B, H)

    char* ws0 = (char*)d_ws;
    size_t off = 0;
    float* qc      = (float*)(ws0 + off);    off += 64 * 512 * 4;
    uint4* WeF     = (uint4*)(ws0 + off);    off += 512 * 512 * 2;
    float* oP      = (float*)(ws0 + off);    off += (size_t)BB * NCH * HD * 4;
    float* lP      = (float*)(ws0 + off);    off += BB * NCH * 4;
    float* x       = (float*)(ws0 + off);    off += 64 * 1024 * 4;
    unsigned* y_bf = (unsigned*)(ws0 + off); off += 64 * 1024 * 2;
    float* gi      = (float*)(ws0 + off);    off += 64 * 1536 * 4;
    float* gh      = (float*)(ws0 + off);    off += 64 * 1536 * 4;
    float* lsmp    = (float*)(ws0 + off);    off += 320 * 2 * 4;

    prep_kernel<<<128, 256, 0, stream>>>(hid, attn_W, attn_b, qc, WeF);
    fattn_kernel<<<BB * NCH, 512, 0, stream>>>(enc, WeF, qc, v, oP, lP);
    combine_kernel<<<BB, 512, 0, stream>>>(oP, lP, word, emb, x, y_bf);
    gates_kernel<<<384, 256, 0, stream>>>(x, hid, W_ih, W_hh, b_ih, b_hh, gi, gh);
    hnew_kernel<<<BB, 256, 0, stream>>>(gi, gh, hid, out_h, y_bf);
    logits_kernel<<<VV / 64, 256, 0, stream>>>((const unsigned short*)y_bf, out_W, out_b, logits);
    lsm1_kernel<<<320, 256, 0, stream>>>(logits, lsmp);
    lsm2_kernel<<<320, 256, 0, stream>>>(logits, lsmp);
}